// Round 12
// baseline (405.121 us; speedup 1.0000x reference)
//
#include <hip/hip_runtime.h>

#define NN 40960
#define NE 655360
#define ET (NE + NN)        // 696320 edges incl self-loops
#define D 128
#define NG 16
#define PL 33280            // params per layer: WF[32768], bf[256], att[128], b[128]

typedef unsigned int u32;
typedef unsigned short u16;
typedef long long i64;

struct P18 { const void* p[18]; };

__device__ __forceinline__ float bf2f(u16 v){ return __uint_as_float(((u32)v)<<16); }
__device__ __forceinline__ u16 f2bf(float f){
  u32 u = __float_as_uint(f);
  return (u16)((u + 0x7FFFu + ((u>>16)&1u)) >> 16);
}
__device__ __forceinline__ int geti(const void* p, long long i, int f64, int bound){
  long long v = f64 ? ((const i64*)p)[i] : (long long)((const int*)p)[i];
  int x = (int)v;
  return (x < 0) ? 0 : ((x >= bound) ? bound-1 : x);
}
__device__ __forceinline__ void stf(void* p, long long i, float v, int isbf){
  if (isbf) ((u16*)p)[i] = f2bf(v); else ((float*)p)[i] = v;
}
__device__ __forceinline__ float rdf(const void* p, int i, int isbf){
  return isbf ? bf2f(((const u16*)p)[i]) : ((const float*)p)[i];
}

// block 0: dtype detect; blocks 1..160: zero cursor; blocks 161..168: zero pool
__global__ void k_setup(const void* __restrict__ ei, const void* __restrict__ x,
                        int* __restrict__ flags, u32* __restrict__ cursor, float* __restrict__ pool){
  int b = blockIdx.x;
  if (b == 0){
    __shared__ int nz, cnt;
    if (threadIdx.x == 0){ nz = 0; cnt = 0; }
    __syncthreads();
    if (((const int*)ei)[2*threadIdx.x + 1] != 0) atomicAdd(&nz, 1);
    if (threadIdx.x < 128){
      u16 v = ((const u16*)x)[2*threadIdx.x];
      int ex = (v >> 7) & 0xFF;
      if (ex >= 100 && ex <= 140) atomicAdd(&cnt, 1);
    }
    __syncthreads();
    if (threadIdx.x == 0){
      flags[0] = (nz == 0) ? 1 : 0;
      flags[1] = (cnt >= 64) ? 1 : 0;
    }
  } else if (b <= 160){
    cursor[(b-1)*256 + threadIdx.x] = 0u;
  } else {
    int i = (b-161)*256 + threadIdx.x;
    if (i < NG*D) pool[i] = 0.f;
  }
}

__global__ void k_cvt(const void* __restrict__ src, float* __restrict__ dst, int n, const int* __restrict__ flags){
  int i = blockIdx.x*256 + threadIdx.x;
  if (i >= n) return;
  dst[i] = rdf(src, i, flags[1]);
}

// all-layer param pack (one launch): blockIdx.y = layer
__global__ void k_cvtp(P18 ps, float* __restrict__ prm, const int* __restrict__ flags){
  int l = blockIdx.y;
  int i = blockIdx.x*256 + threadIdx.x;
  if (i >= PL) return;
  const void* Wl  = ps.p[6*l+0];
  const void* bl  = ps.p[6*l+1];
  const void* Wr  = ps.p[6*l+2];
  const void* br  = ps.p[6*l+3];
  const void* att = ps.p[6*l+4];
  const void* b   = ps.p[6*l+5];
  int isbf = flags[1];
  float v;
  if (i < 32768){
    int k = i >> 8, gc = i & 255;
    v = (gc < 128) ? rdf(Wl, k*128 + gc, isbf) : rdf(Wr, k*128 + gc - 128, isbf);
  }
  else if (i < 33024){ int gc = i - 32768; v = (gc < 128) ? rdf(bl, gc, isbf) : rdf(br, gc - 128, isbf); }
  else if (i < 33152) v = rdf(att, i - 33024, isbf);
  else                v = rdf(b, i - 33152, isbf);
  prm[(size_t)l*PL + i] = v;
}

// ---------- CSR build (by dst, self-loops appended); entry packs src|dst<<16 ----------
__global__ void k_hist(const void* __restrict__ ei, u32* __restrict__ cursor, const int* __restrict__ flags){
  int e = blockIdx.x*256 + threadIdx.x;
  if (e >= ET) return;
  int dd = (e < NE) ? geti(ei, (long long)NE + e, flags[0], NN) : e - NE;
  atomicAdd(&cursor[dd], 1u);
}

__global__ __launch_bounds__(1024) void k_scan(u32* __restrict__ cursor, u32* __restrict__ offs){
  __shared__ u32 part[1024];
  int t = threadIdx.x;
  int base = t * 40;
  u32 s = 0;
  #pragma unroll 4
  for (int i = 0; i < 40; ++i) s += cursor[base + i];
  part[t] = s;
  __syncthreads();
  for (int off = 1; off < 1024; off <<= 1){
    u32 v = (t >= off) ? part[t - off] : 0u;
    __syncthreads();
    part[t] += v;
    __syncthreads();
  }
  u32 run = (t == 0) ? 0u : part[t - 1];
  for (int i = 0; i < 40; ++i){
    u32 d = cursor[base + i];
    offs[base + i] = run;
    cursor[base + i] = run;
    run += d;
  }
  if (t == 1023) offs[NN] = run;
}

__global__ void k_scatter(const void* __restrict__ ei, u32* __restrict__ cursor,
                          u32* __restrict__ csr, const int* __restrict__ flags){
  int e = blockIdx.x*256 + threadIdx.x;
  if (e >= ET) return;
  int f = flags[0];
  int s, dd;
  if (e < NE){ s = geti(ei, e, f, NN); dd = geti(ei, (long long)NE + e, f, NN); }
  else { s = dd = e - NE; }
  u32 pos = atomicAdd(&cursor[dd], 1u);
  csr[pos] = (u32)s | ((u32)dd << 16);
}

__global__ void k_bounds(const void* __restrict__ batch, u32* __restrict__ bnd, const int* __restrict__ flags){
  int g = threadIdx.x;
  if (g > NG) return;
  if (g == NG){ bnd[NG] = NN; return; }
  int f = flags[0];
  int lo = 0, hi = NN;
  while (lo < hi){
    int mid = (lo + hi) >> 1;
    if (geti(batch, mid, f, NG) < g) lo = mid + 1; else hi = mid;
  }
  bnd[g] = (u32)lo;
}

// ---------- GEMM: 128 rows x 128 cols per block, BK=64, 8x8 quadrant micro-tile ----------
// Per k: 64 FMA vs 4 LDS b128 -> VALU-dominant. X global re-read 2x (was 4x).
// Xs stage scalar-scatter with XOR swizzle (R9-proven); Ws contiguous b128 runs.
// LDS 64KB -> 2 blocks/CU.
__global__ __launch_bounds__(256, 2) void k_gemm(const float* __restrict__ X, const float* __restrict__ pr,
                                                 float* __restrict__ xl, float* __restrict__ xr)
{
  __shared__ float Xs[64][128];   // [k][row], row XOR-swizzled within 64-groups
  __shared__ float Ws[64][128];   // [k][col]
  int tid = threadIdx.x;
  int row0 = blockIdx.x * 128;
  int bc0  = blockIdx.y * 128;    // 0 -> xl cols, 128 -> xr cols
  int ty = tid >> 4, tx = tid & 15;
  int r = ty*4, cA = tx*4;

  float4 bv0 = *(const float4*)(pr + 32768 + bc0 + cA);
  float4 bv1 = *(const float4*)(pr + 32768 + bc0 + cA + 64);
  float acc[2][2][4][4];
  #pragma unroll
  for (int qr = 0; qr < 2; ++qr)
    #pragma unroll
    for (int i = 0; i < 4; ++i){
      acc[qr][0][i][0] = bv0.x; acc[qr][0][i][1] = bv0.y;
      acc[qr][0][i][2] = bv0.z; acc[qr][0][i][3] = bv0.w;
      acc[qr][1][i][0] = bv1.x; acc[qr][1][i][1] = bv1.y;
      acc[qr][1][i][2] = bv1.z; acc[qr][1][i][3] = bv1.w;
    }

  #pragma unroll
  for (int kt = 0; kt < 2; ++kt){
    const float* Xb = X + (size_t)row0*D + kt*64;
    #pragma unroll
    for (int i = 0; i < 8; ++i){
      int idx = tid + i*256;
      int row = idx >> 4, k4 = idx & 15;
      float4 v = *(const float4*)(Xb + (size_t)row*D + k4*4);
      int rs = row ^ (k4 << 2);     // flips low 6 bits only: stays in row's 64-group
      Xs[k4*4+0][rs] = v.x;
      Xs[k4*4+1][rs] = v.y;
      Xs[k4*4+2][rs] = v.z;
      Xs[k4*4+3][rs] = v.w;
    }
    const float* Wb = pr + (size_t)kt*64*256 + bc0;
    #pragma unroll
    for (int i = 0; i < 8; ++i){
      int idx = tid + i*256;
      int k = idx >> 5, c4 = idx & 31;
      *(float4*)&Ws[k][c4*4] = *(const float4*)(Wb + (size_t)k*256 + c4*4);
    }
    __syncthreads();
    #pragma unroll 2
    for (int k = 0; k < 64; ++k){
      int swb = (k >> 2) << 2;
      int ra = r ^ swb;
      float4 a0 = *(const float4*)&Xs[k][ra];
      float4 a1 = *(const float4*)&Xs[k][ra + 64];
      float4 w0 = *(const float4*)&Ws[k][cA];
      float4 w1 = *(const float4*)&Ws[k][cA + 64];
      #pragma unroll
      for (int qr = 0; qr < 2; ++qr){
        float ax = qr ? a1.x : a0.x, ay = qr ? a1.y : a0.y;
        float az = qr ? a1.z : a0.z, aw = qr ? a1.w : a0.w;
        #pragma unroll
        for (int qc = 0; qc < 2; ++qc){
          float wx = qc ? w1.x : w0.x, wy = qc ? w1.y : w0.y;
          float wz = qc ? w1.z : w0.z, ww = qc ? w1.w : w0.w;
          acc[qr][qc][0][0] = fmaf(ax, wx, acc[qr][qc][0][0]);
          acc[qr][qc][0][1] = fmaf(ax, wy, acc[qr][qc][0][1]);
          acc[qr][qc][0][2] = fmaf(ax, wz, acc[qr][qc][0][2]);
          acc[qr][qc][0][3] = fmaf(ax, ww, acc[qr][qc][0][3]);
          acc[qr][qc][1][0] = fmaf(ay, wx, acc[qr][qc][1][0]);
          acc[qr][qc][1][1] = fmaf(ay, wy, acc[qr][qc][1][1]);
          acc[qr][qc][1][2] = fmaf(ay, wz, acc[qr][qc][1][2]);
          acc[qr][qc][1][3] = fmaf(ay, ww, acc[qr][qc][1][3]);
          acc[qr][qc][2][0] = fmaf(az, wx, acc[qr][qc][2][0]);
          acc[qr][qc][2][1] = fmaf(az, wy, acc[qr][qc][2][1]);
          acc[qr][qc][2][2] = fmaf(az, wz, acc[qr][qc][2][2]);
          acc[qr][qc][2][3] = fmaf(az, ww, acc[qr][qc][2][3]);
          acc[qr][qc][3][0] = fmaf(aw, wx, acc[qr][qc][3][0]);
          acc[qr][qc][3][1] = fmaf(aw, wy, acc[qr][qc][3][1]);
          acc[qr][qc][3][2] = fmaf(aw, wz, acc[qr][qc][3][2]);
          acc[qr][qc][3][3] = fmaf(aw, ww, acc[qr][qc][3][3]);
        }
      }
    }
    __syncthreads();
  }

  float* base = bc0 ? xr : xl;
  #pragma unroll
  for (int qr = 0; qr < 2; ++qr)
    #pragma unroll
    for (int i = 0; i < 4; ++i){
      int grow = row0 + qr*64 + r + i;
      *(float4*)(base + (size_t)grow*D + cA) =
          make_float4(acc[qr][0][i][0], acc[qr][0][i][1], acc[qr][0][i][2], acc[qr][0][i][3]);
      *(float4*)(base + (size_t)grow*D + cA + 64) =
          make_float4(acc[qr][1][i][0], acc[qr][1][i][1], acc[qr][1][i][2], acc[qr][1][i][3]);
    }
}

// ---------- fused per-node attention: wave/node, depth-2 pipelined gather, defer-max ----------
// Each half-wave owns edges j0+half, +2, +4 ... ; processes 2 per iter with the next
// pair's gathers issued before computing the current pair.
__global__ __launch_bounds__(256) void k_node(const float* __restrict__ xl, const float* __restrict__ xr,
    const u32* __restrict__ offs, const u32* __restrict__ csr, const float* __restrict__ pr,
    float* __restrict__ hnew, void* __restrict__ out, const int* __restrict__ flags, int last)
{
  int node = blockIdx.x*4 + (threadIdx.x >> 6);
  int lane = threadIdx.x & 63;
  int half = lane >> 5;
  int c = (lane & 31) * 4;
  float4 xrv  = *(const float4*)(xr + (size_t)node*D + c);
  float4 attv = *(const float4*)(pr + 33024 + c);
  u32 j0 = offs[node], j1 = offs[node + 1];

  float mx = -1e30f, ssum = 0.f;
  float4 acc = make_float4(0.f, 0.f, 0.f, 0.f);

  #define SRCJ(jj) ((int)(csr[(jj) < j1 ? (jj) : j0] & 0xFFFFu))
  u32 j = j0 + half;
  int s0 = SRCJ(j), s1 = SRCJ(j+2);
  float4 g0 = *(const float4*)(xl + (size_t)s0*D + c);
  float4 g1 = *(const float4*)(xl + (size_t)s1*D + c);
  int s2 = SRCJ(j+4), s3 = SRCJ(j+6);

  for (; j < j1; j += 4){
    // issue next pair's gathers + csr prefetch before touching g0/g1
    float4 n0 = *(const float4*)(xl + (size_t)s2*D + c);
    float4 n1 = *(const float4*)(xl + (size_t)s3*D + c);
    int t0 = SRCJ(j+8), t1 = SRCJ(j+10);

    {
      float m, p;
      m = g0.x + xrv.x; p = fmaxf(m, 0.2f*m) * attv.x;
      m = g0.y + xrv.y; p = fmaf(fmaxf(m, 0.2f*m), attv.y, p);
      m = g0.z + xrv.z; p = fmaf(fmaxf(m, 0.2f*m), attv.z, p);
      m = g0.w + xrv.w; p = fmaf(fmaxf(m, 0.2f*m), attv.w, p);
      p += __shfl_xor(p, 1, 64);
      p += __shfl_xor(p, 2, 64);
      p += __shfl_xor(p, 4, 64);
      if (p > mx + 8.f){
        float eo = __expf(mx - p);
        ssum  *= eo;
        acc.x *= eo; acc.y *= eo; acc.z *= eo; acc.w *= eo;
        mx = p;
      }
      float en = __expf(p - mx);
      ssum += en;
      acc.x = fmaf(en, g0.x, acc.x);
      acc.y = fmaf(en, g0.y, acc.y);
      acc.z = fmaf(en, g0.z, acc.z);
      acc.w = fmaf(en, g0.w, acc.w);
    }
    if (j + 2 < j1){
      float m, p;
      m = g1.x + xrv.x; p = fmaxf(m, 0.2f*m) * attv.x;
      m = g1.y + xrv.y; p = fmaf(fmaxf(m, 0.2f*m), attv.y, p);
      m = g1.z + xrv.z; p = fmaf(fmaxf(m, 0.2f*m), attv.z, p);
      m = g1.w + xrv.w; p = fmaf(fmaxf(m, 0.2f*m), attv.w, p);
      p += __shfl_xor(p, 1, 64);
      p += __shfl_xor(p, 2, 64);
      p += __shfl_xor(p, 4, 64);
      if (p > mx + 8.f){
        float eo = __expf(mx - p);
        ssum  *= eo;
        acc.x *= eo; acc.y *= eo; acc.z *= eo; acc.w *= eo;
        mx = p;
      }
      float en = __expf(p - mx);
      ssum += en;
      acc.x = fmaf(en, g1.x, acc.x);
      acc.y = fmaf(en, g1.y, acc.y);
      acc.z = fmaf(en, g1.z, acc.z);
      acc.w = fmaf(en, g1.w, acc.w);
    }
    g0 = n0; g1 = n1; s2 = t0; s3 = t1;
  }
  #undef SRCJ

  // merge the two half-wave states (lanes l and l+32 share channels)
  float mo = __shfl_xor(mx, 32, 64);
  float so = __shfl_xor(ssum, 32, 64);
  float ax = __shfl_xor(acc.x, 32, 64);
  float ay = __shfl_xor(acc.y, 32, 64);
  float az = __shfl_xor(acc.z, 32, 64);
  float aw = __shfl_xor(acc.w, 32, 64);
  float n  = fmaxf(mx, mo);
  float e0 = __expf(mx - n), e1 = __expf(mo - n);
  ssum  = ssum*e0 + so*e1;
  acc.x = acc.x*e0 + ax*e1;
  acc.y = acc.y*e0 + ay*e1;
  acc.z = acc.z*e0 + az*e1;
  acc.w = acc.w*e0 + aw*e1;

  if (half == 0){
    float inv = 1.0f / fmaxf(ssum, 1e-30f);
    float4 bv = *(const float4*)(pr + 33152 + c);
    float4 v = make_float4(acc.x*inv + bv.x, acc.y*inv + bv.y,
                           acc.z*inv + bv.z, acc.w*inv + bv.w);
    if (!last){
      v.x = fmaxf(v.x, 0.f); v.y = fmaxf(v.y, 0.f);
      v.z = fmaxf(v.z, 0.f); v.w = fmaxf(v.w, 0.f);
      *(float4*)(hnew + (size_t)node*D + c) = v;
    } else {
      *(float4*)(hnew + (size_t)node*D + c) = v;
      int isbf = flags[1];
      long long o = (long long)NG*D + (long long)node*D + c;
      stf(out, o+0, v.x, isbf); stf(out, o+1, v.y, isbf);
      stf(out, o+2, v.z, isbf); stf(out, o+3, v.w, isbf);
    }
  }
}

// ---------- two-stage mean pool ----------
__global__ __launch_bounds__(256) void k_pool1(const float* __restrict__ h, const u32* __restrict__ bnd,
                                               float* __restrict__ pool){
  int g = blockIdx.x >> 6, sl = blockIdx.x & 63;
  int ch = threadIdx.x & 127, ro = threadIdx.x >> 7;
  u32 b0 = bnd[g], b1 = bnd[g + 1];
  float acc = 0.f;
  for (u32 r = b0 + sl*2 + ro; r < b1; r += 128) acc += h[(size_t)r*D + ch];
  unsafeAtomicAdd(&pool[g*D + ch], acc);
}

__global__ void k_pool2(const float* __restrict__ pool, const u32* __restrict__ bnd,
                        void* __restrict__ out, const int* __restrict__ flags){
  int i = blockIdx.x*256 + threadIdx.x;
  if (i >= NG*D) return;
  int g = i >> 7;
  float c = (float)(bnd[g + 1] - bnd[g]);
  stf(out, i, pool[i] / fmaxf(c, 1.f), flags[1]);
}

extern "C" void kernel_launch(void* const* d_in, const int* in_sizes, int n_in,
                              void* d_out, int out_size, void* d_ws, size_t ws_size,
                              hipStream_t stream) {
  const void* x     = d_in[0];
  const void* ei    = d_in[1];
  const void* batch = d_in[2];

  const long long nf = (long long)NN*D*3 + 3*PL + NG*D;
  const long long nu = (NN + 1) + NN + ET + (NG + 1) + 2;
  if (ws_size < (size_t)(nf + nu)*4 + 256) return;

  float* ws    = (float*)d_ws;
  float* xf    = ws;                               // NN*D (h buffer each layer)
  float* xl    = xf + (size_t)NN*D;
  float* xr    = xl + (size_t)NN*D;
  float* prm   = xr + (size_t)NN*D;                // 3*PL
  float* pool  = prm + 3*PL;                       // NG*D
  u32*  offs   = (u32*)(pool + NG*D);              // NN+1
  u32*  cursor = offs + (NN + 1);                  // NN
  u32*  csr    = cursor + NN;                      // ET
  u32*  bnd    = csr + ET;                         // NG+1
  int*  flags  = (int*)(bnd + (NG + 1));           // 2

  k_setup<<<169, 256, 0, stream>>>(ei, x, flags, cursor, pool);
  k_cvt<<<(NN*D)/256, 256, 0, stream>>>(x, xf, NN*D, flags);
  P18 ps;
  for (int i = 0; i < 18; ++i) ps.p[i] = d_in[3 + i];
  k_cvtp<<<dim3((PL + 255)/256, 3), 256, 0, stream>>>(ps, prm, flags);

  k_hist<<<ET/256, 256, 0, stream>>>(ei, cursor, flags);
  k_scan<<<1, 1024, 0, stream>>>(cursor, offs);
  k_scatter<<<ET/256, 256, 0, stream>>>(ei, cursor, csr, flags);
  k_bounds<<<1, 32, 0, stream>>>(batch, bnd, flags);

  for (int l = 0; l < 3; ++l){
    const float* p = prm + (size_t)l*PL;
    k_gemm<<<dim3(NN/128, 2), 256, 0, stream>>>(xf, p, xl, xr);
    k_node<<<NN/4, 256, 0, stream>>>(xl, xr, offs, csr, p, xf, d_out, flags, l == 2);
  }
  k_pool1<<<NG*64, 256, 0, stream>>>(xf, bnd, pool);
  k_pool2<<<8, 256, 0, stream>>>(pool, bnd, d_out, flags);
}

// Round 13
// 396.617 us; speedup vs baseline: 1.0214x; 1.0214x over previous
//
#include <hip/hip_runtime.h>

#define NN 40960
#define NE 655360
#define ET (NE + NN)        // 696320 edges incl self-loops
#define D 128
#define NG 16
#define PL 33280            // params per layer: WF[32768], bf[256], att[128], b[128]

typedef unsigned int u32;
typedef unsigned short u16;
typedef long long i64;

struct P18 { const void* p[18]; };

__device__ __forceinline__ float bf2f(u16 v){ return __uint_as_float(((u32)v)<<16); }
__device__ __forceinline__ u16 f2bf(float f){
  u32 u = __float_as_uint(f);
  return (u16)((u + 0x7FFFu + ((u>>16)&1u)) >> 16);
}
__device__ __forceinline__ int geti(const void* p, long long i, int f64, int bound){
  long long v = f64 ? ((const i64*)p)[i] : (long long)((const int*)p)[i];
  int x = (int)v;
  return (x < 0) ? 0 : ((x >= bound) ? bound-1 : x);
}
__device__ __forceinline__ void stf(void* p, long long i, float v, int isbf){
  if (isbf) ((u16*)p)[i] = f2bf(v); else ((float*)p)[i] = v;
}
__device__ __forceinline__ float rdf(const void* p, int i, int isbf){
  return isbf ? bf2f(((const u16*)p)[i]) : ((const float*)p)[i];
}

// block 0: dtype detect; blocks 1..160: zero cursor; blocks 161..168: zero pool
__global__ void k_setup(const void* __restrict__ ei, const void* __restrict__ x,
                        int* __restrict__ flags, u32* __restrict__ cursor, float* __restrict__ pool){
  int b = blockIdx.x;
  if (b == 0){
    __shared__ int nz, cnt;
    if (threadIdx.x == 0){ nz = 0; cnt = 0; }
    __syncthreads();
    if (((const int*)ei)[2*threadIdx.x + 1] != 0) atomicAdd(&nz, 1);
    if (threadIdx.x < 128){
      u16 v = ((const u16*)x)[2*threadIdx.x];
      int ex = (v >> 7) & 0xFF;
      if (ex >= 100 && ex <= 140) atomicAdd(&cnt, 1);
    }
    __syncthreads();
    if (threadIdx.x == 0){
      flags[0] = (nz == 0) ? 1 : 0;
      flags[1] = (cnt >= 64) ? 1 : 0;
    }
  } else if (b <= 160){
    cursor[(b-1)*256 + threadIdx.x] = 0u;
  } else {
    int i = (b-161)*256 + threadIdx.x;
    if (i < NG*D) pool[i] = 0.f;
  }
}

// blocks [0,20480): x->f32 ; blocks [20480, 20480+390): param pack (130/layer)
__global__ void k_prep(P18 ps, const void* __restrict__ x, float* __restrict__ xf,
                       float* __restrict__ prm, const int* __restrict__ flags){
  int b = blockIdx.x;
  int isbf = flags[1];
  if (b < 20480){
    int i = b*256 + threadIdx.x;
    xf[i] = rdf(x, i, isbf);
    return;
  }
  b -= 20480;
  int l = b / 130;
  int i = (b % 130)*256 + threadIdx.x;
  const void* Wl  = ps.p[6*l+0];
  const void* bl  = ps.p[6*l+1];
  const void* Wr  = ps.p[6*l+2];
  const void* br  = ps.p[6*l+3];
  const void* att = ps.p[6*l+4];
  const void* bb  = ps.p[6*l+5];
  float v;
  if (i < 32768){
    int k = i >> 8, gc = i & 255;
    v = (gc < 128) ? rdf(Wl, k*128 + gc, isbf) : rdf(Wr, k*128 + gc - 128, isbf);
  }
  else if (i < 33024){ int gc = i - 32768; v = (gc < 128) ? rdf(bl, gc, isbf) : rdf(br, gc - 128, isbf); }
  else if (i < 33152) v = rdf(att, i - 33024, isbf);
  else                v = rdf(bb, i - 33152, isbf);
  prm[(size_t)l*PL + i] = v;
}

// ---------- CSR build (by dst, self-loops appended); entry packs src|dst<<16 ----------
__global__ void k_hist(const void* __restrict__ ei, u32* __restrict__ cursor, const int* __restrict__ flags){
  int e = blockIdx.x*256 + threadIdx.x;
  if (e >= ET) return;
  int dd = (e < NE) ? geti(ei, (long long)NE + e, flags[0], NN) : e - NE;
  atomicAdd(&cursor[dd], 1u);
}

// block 0: exclusive scan; block 1: graph bounds via binary search
__global__ __launch_bounds__(1024) void k_scan(u32* __restrict__ cursor, u32* __restrict__ offs,
                                               const void* __restrict__ batch, u32* __restrict__ bnd,
                                               const int* __restrict__ flags){
  if (blockIdx.x == 1){
    int g = threadIdx.x;
    if (g > NG) return;
    if (g == NG){ bnd[NG] = NN; return; }
    int f = flags[0];
    int lo = 0, hi = NN;
    while (lo < hi){
      int mid = (lo + hi) >> 1;
      if (geti(batch, mid, f, NG) < g) lo = mid + 1; else hi = mid;
    }
    bnd[g] = (u32)lo;
    return;
  }
  __shared__ u32 part[1024];
  int t = threadIdx.x;
  int base = t * 40;
  u32 s = 0;
  #pragma unroll 4
  for (int i = 0; i < 40; ++i) s += cursor[base + i];
  part[t] = s;
  __syncthreads();
  for (int off = 1; off < 1024; off <<= 1){
    u32 v = (t >= off) ? part[t - off] : 0u;
    __syncthreads();
    part[t] += v;
    __syncthreads();
  }
  u32 run = (t == 0) ? 0u : part[t - 1];
  for (int i = 0; i < 40; ++i){
    u32 d = cursor[base + i];
    offs[base + i] = run;
    cursor[base + i] = run;
    run += d;
  }
  if (t == 1023) offs[NN] = run;
}

__global__ void k_scatter(const void* __restrict__ ei, u32* __restrict__ cursor,
                          u32* __restrict__ csr, const int* __restrict__ flags){
  int e = blockIdx.x*256 + threadIdx.x;
  if (e >= ET) return;
  int f = flags[0];
  int s, dd;
  if (e < NE){ s = geti(ei, e, f, NN); dd = geti(ei, (long long)NE + e, f, NN); }
  else { s = dd = e - NE; }
  u32 pos = atomicAdd(&cursor[dd], 1u);
  csr[pos] = (u32)s | ((u32)dd << 16);
}

// ---------- GEMM: 128 rows x 64 cols per block, BK=32 x 4 tiles, reg-double-buffered ----------
// Next tile's global loads issue before current tile's compute -> latency hidden.
// LDS 24KB -> no LDS cap; __launch_bounds__(256,4) -> 4 blocks/CU.
__global__ __launch_bounds__(256, 4) void k_gemm(const float* __restrict__ X, const float* __restrict__ pr,
                                                 float* __restrict__ xl, float* __restrict__ xr)
{
  __shared__ float Xs[32][128];   // [k][row], row XOR-swizzled
  __shared__ float Ws[32][64];    // [k][col]
  int tid = threadIdx.x;
  int row0 = blockIdx.x * 128;
  int bc0  = blockIdx.y * 64;
  int ty = tid >> 4, tx = tid & 15;
  int r = ty*4, c = tx*4;

  float4 bias = *(const float4*)(pr + 32768 + bc0 + c);
  float acc[8][4];
  #pragma unroll
  for (int i = 0; i < 8; ++i){
    acc[i][0] = bias.x; acc[i][1] = bias.y; acc[i][2] = bias.z; acc[i][3] = bias.w;
  }

  // staging registers
  float4 xv[4], wv[2];
  // addressing (constant across kt): X part
  int xrow[4], xk4[4];
  #pragma unroll
  for (int i = 0; i < 4; ++i){
    int idx = tid + i*256;
    xrow[i] = idx >> 3;          // 0..127
    xk4[i]  = idx & 7;           // float4 index within 32-k row
  }
  int wk = 0, wc4 = 0;
  {
    int idx = tid;
    wk = idx >> 4; wc4 = idx & 15;
  }

  // load kt=0
  #pragma unroll
  for (int i = 0; i < 4; ++i)
    xv[i] = *(const float4*)(X + (size_t)(row0 + xrow[i])*D + 0*32 + xk4[i]*4);
  #pragma unroll
  for (int i = 0; i < 2; ++i){
    int idx = tid + i*256;
    int k = idx >> 4, c4 = idx & 15;
    wv[i] = *(const float4*)(pr + (size_t)(0*32 + k)*256 + bc0 + c4*4);
  }

  #pragma unroll
  for (int kt = 0; kt < 4; ++kt){
    __syncthreads();               // prev compute done reading LDS
    #pragma unroll
    for (int i = 0; i < 4; ++i){
      int rs = xrow[i] ^ (xk4[i] << 2);
      Xs[xk4[i]*4+0][rs] = xv[i].x;
      Xs[xk4[i]*4+1][rs] = xv[i].y;
      Xs[xk4[i]*4+2][rs] = xv[i].z;
      Xs[xk4[i]*4+3][rs] = xv[i].w;
    }
    #pragma unroll
    for (int i = 0; i < 2; ++i){
      int idx = tid + i*256;
      int k = idx >> 4, c4 = idx & 15;
      *(float4*)&Ws[k][c4*4] = wv[i];
    }
    __syncthreads();
    if (kt < 3){                   // issue next tile's loads (hidden under compute)
      #pragma unroll
      for (int i = 0; i < 4; ++i)
        xv[i] = *(const float4*)(X + (size_t)(row0 + xrow[i])*D + (kt+1)*32 + xk4[i]*4);
      #pragma unroll
      for (int i = 0; i < 2; ++i){
        int idx = tid + i*256;
        int k = idx >> 4, c4 = idx & 15;
        wv[i] = *(const float4*)(pr + (size_t)((kt+1)*32 + k)*256 + bc0 + c4*4);
      }
    }
    #pragma unroll 4
    for (int k = 0; k < 32; ++k){
      int swb = ((k >> 2) & 7) << 2;
      int ra = r ^ swb;
      float4 a0 = *(const float4*)&Xs[k][ra];
      float4 a1 = *(const float4*)&Xs[k][ra + 64];
      float4 b = *(const float4*)&Ws[k][c];
      acc[0][0] = fmaf(a0.x, b.x, acc[0][0]); acc[0][1] = fmaf(a0.x, b.y, acc[0][1]);
      acc[0][2] = fmaf(a0.x, b.z, acc[0][2]); acc[0][3] = fmaf(a0.x, b.w, acc[0][3]);
      acc[1][0] = fmaf(a0.y, b.x, acc[1][0]); acc[1][1] = fmaf(a0.y, b.y, acc[1][1]);
      acc[1][2] = fmaf(a0.y, b.z, acc[1][2]); acc[1][3] = fmaf(a0.y, b.w, acc[1][3]);
      acc[2][0] = fmaf(a0.z, b.x, acc[2][0]); acc[2][1] = fmaf(a0.z, b.y, acc[2][1]);
      acc[2][2] = fmaf(a0.z, b.z, acc[2][2]); acc[2][3] = fmaf(a0.z, b.w, acc[2][3]);
      acc[3][0] = fmaf(a0.w, b.x, acc[3][0]); acc[3][1] = fmaf(a0.w, b.y, acc[3][1]);
      acc[3][2] = fmaf(a0.w, b.z, acc[3][2]); acc[3][3] = fmaf(a0.w, b.w, acc[3][3]);
      acc[4][0] = fmaf(a1.x, b.x, acc[4][0]); acc[4][1] = fmaf(a1.x, b.y, acc[4][1]);
      acc[4][2] = fmaf(a1.x, b.z, acc[4][2]); acc[4][3] = fmaf(a1.x, b.w, acc[4][3]);
      acc[5][0] = fmaf(a1.y, b.x, acc[5][0]); acc[5][1] = fmaf(a1.y, b.y, acc[5][1]);
      acc[5][2] = fmaf(a1.y, b.z, acc[5][2]); acc[5][3] = fmaf(a1.y, b.w, acc[5][3]);
      acc[6][0] = fmaf(a1.z, b.x, acc[6][0]); acc[6][1] = fmaf(a1.z, b.y, acc[6][1]);
      acc[6][2] = fmaf(a1.z, b.z, acc[6][2]); acc[6][3] = fmaf(a1.z, b.w, acc[6][3]);
      acc[7][0] = fmaf(a1.w, b.x, acc[7][0]); acc[7][1] = fmaf(a1.w, b.y, acc[7][1]);
      acc[7][2] = fmaf(a1.w, b.z, acc[7][2]); acc[7][3] = fmaf(a1.w, b.w, acc[7][3]);
    }
  }

  float* base = (bc0 < 128) ? xl : xr;
  int co = (bc0 < 128) ? bc0 + c : bc0 - 128 + c;
  #pragma unroll
  for (int i = 0; i < 4; ++i){
    *(float4*)(base + (size_t)(row0 + r + i)*D + co) =
        make_float4(acc[i][0], acc[i][1], acc[i][2], acc[i][3]);
    *(float4*)(base + (size_t)(row0 + 64 + r + i)*D + co) =
        make_float4(acc[4+i][0], acc[4+i][1], acc[4+i][2], acc[4+i][3]);
  }
}

// ---------- fused per-node attention: wave/node, depth-2 pipelined gather, defer-max ----------
__global__ __launch_bounds__(256) void k_node(const float* __restrict__ xl, const float* __restrict__ xr,
    const u32* __restrict__ offs, const u32* __restrict__ csr, const float* __restrict__ pr,
    float* __restrict__ hnew, void* __restrict__ out, const int* __restrict__ flags, int last)
{
  int node = blockIdx.x*4 + (threadIdx.x >> 6);
  int lane = threadIdx.x & 63;
  int half = lane >> 5;
  int c = (lane & 31) * 4;
  float4 xrv  = *(const float4*)(xr + (size_t)node*D + c);
  float4 attv = *(const float4*)(pr + 33024 + c);
  u32 j0 = offs[node], j1 = offs[node + 1];

  float mx = -1e30f, ssum = 0.f;
  float4 acc = make_float4(0.f, 0.f, 0.f, 0.f);

  #define SRCJ(jj) ((int)(csr[(jj) < j1 ? (jj) : j0] & 0xFFFFu))
  u32 j = j0 + half;
  int s0 = SRCJ(j), s1 = SRCJ(j+2);
  float4 g0 = *(const float4*)(xl + (size_t)s0*D + c);
  float4 g1 = *(const float4*)(xl + (size_t)s1*D + c);
  int s2 = SRCJ(j+4), s3 = SRCJ(j+6);

  for (; j < j1; j += 4){
    float4 n0 = *(const float4*)(xl + (size_t)s2*D + c);
    float4 n1 = *(const float4*)(xl + (size_t)s3*D + c);
    int t0 = SRCJ(j+8), t1 = SRCJ(j+10);

    {
      float m, p;
      m = g0.x + xrv.x; p = fmaxf(m, 0.2f*m) * attv.x;
      m = g0.y + xrv.y; p = fmaf(fmaxf(m, 0.2f*m), attv.y, p);
      m = g0.z + xrv.z; p = fmaf(fmaxf(m, 0.2f*m), attv.z, p);
      m = g0.w + xrv.w; p = fmaf(fmaxf(m, 0.2f*m), attv.w, p);
      p += __shfl_xor(p, 1, 64);
      p += __shfl_xor(p, 2, 64);
      p += __shfl_xor(p, 4, 64);
      if (p > mx + 8.f){
        float eo = __expf(mx - p);
        ssum  *= eo;
        acc.x *= eo; acc.y *= eo; acc.z *= eo; acc.w *= eo;
        mx = p;
      }
      float en = __expf(p - mx);
      ssum += en;
      acc.x = fmaf(en, g0.x, acc.x);
      acc.y = fmaf(en, g0.y, acc.y);
      acc.z = fmaf(en, g0.z, acc.z);
      acc.w = fmaf(en, g0.w, acc.w);
    }
    if (j + 2 < j1){
      float m, p;
      m = g1.x + xrv.x; p = fmaxf(m, 0.2f*m) * attv.x;
      m = g1.y + xrv.y; p = fmaf(fmaxf(m, 0.2f*m), attv.y, p);
      m = g1.z + xrv.z; p = fmaf(fmaxf(m, 0.2f*m), attv.z, p);
      m = g1.w + xrv.w; p = fmaf(fmaxf(m, 0.2f*m), attv.w, p);
      p += __shfl_xor(p, 1, 64);
      p += __shfl_xor(p, 2, 64);
      p += __shfl_xor(p, 4, 64);
      if (p > mx + 8.f){
        float eo = __expf(mx - p);
        ssum  *= eo;
        acc.x *= eo; acc.y *= eo; acc.z *= eo; acc.w *= eo;
        mx = p;
      }
      float en = __expf(p - mx);
      ssum += en;
      acc.x = fmaf(en, g1.x, acc.x);
      acc.y = fmaf(en, g1.y, acc.y);
      acc.z = fmaf(en, g1.z, acc.z);
      acc.w = fmaf(en, g1.w, acc.w);
    }
    g0 = n0; g1 = n1; s2 = t0; s3 = t1;
  }
  #undef SRCJ

  float mo = __shfl_xor(mx, 32, 64);
  float so = __shfl_xor(ssum, 32, 64);
  float ax = __shfl_xor(acc.x, 32, 64);
  float ay = __shfl_xor(acc.y, 32, 64);
  float az = __shfl_xor(acc.z, 32, 64);
  float aw = __shfl_xor(acc.w, 32, 64);
  float n  = fmaxf(mx, mo);
  float e0 = __expf(mx - n), e1 = __expf(mo - n);
  ssum  = ssum*e0 + so*e1;
  acc.x = acc.x*e0 + ax*e1;
  acc.y = acc.y*e0 + ay*e1;
  acc.z = acc.z*e0 + az*e1;
  acc.w = acc.w*e0 + aw*e1;

  if (half == 0){
    float inv = 1.0f / fmaxf(ssum, 1e-30f);
    float4 bv = *(const float4*)(pr + 33152 + c);
    float4 v = make_float4(acc.x*inv + bv.x, acc.y*inv + bv.y,
                           acc.z*inv + bv.z, acc.w*inv + bv.w);
    if (!last){
      v.x = fmaxf(v.x, 0.f); v.y = fmaxf(v.y, 0.f);
      v.z = fmaxf(v.z, 0.f); v.w = fmaxf(v.w, 0.f);
      *(float4*)(hnew + (size_t)node*D + c) = v;
    } else {
      *(float4*)(hnew + (size_t)node*D + c) = v;
      int isbf = flags[1];
      long long o = (long long)NG*D + (long long)node*D + c;
      stf(out, o+0, v.x, isbf); stf(out, o+1, v.y, isbf);
      stf(out, o+2, v.z, isbf); stf(out, o+3, v.w, isbf);
    }
  }
}

// ---------- two-stage mean pool ----------
__global__ __launch_bounds__(256) void k_pool1(const float* __restrict__ h, const u32* __restrict__ bnd,
                                               float* __restrict__ pool){
  int g = blockIdx.x >> 6, sl = blockIdx.x & 63;
  int ch = threadIdx.x & 127, ro = threadIdx.x >> 7;
  u32 b0 = bnd[g], b1 = bnd[g + 1];
  float acc = 0.f;
  for (u32 r = b0 + sl*2 + ro; r < b1; r += 128) acc += h[(size_t)r*D + ch];
  unsafeAtomicAdd(&pool[g*D + ch], acc);
}

__global__ void k_pool2(const float* __restrict__ pool, const u32* __restrict__ bnd,
                        void* __restrict__ out, const int* __restrict__ flags){
  int i = blockIdx.x*256 + threadIdx.x;
  if (i >= NG*D) return;
  int g = i >> 7;
  float c = (float)(bnd[g + 1] - bnd[g]);
  stf(out, i, pool[i] / fmaxf(c, 1.f), flags[1]);
}

extern "C" void kernel_launch(void* const* d_in, const int* in_sizes, int n_in,
                              void* d_out, int out_size, void* d_ws, size_t ws_size,
                              hipStream_t stream) {
  const void* x     = d_in[0];
  const void* ei    = d_in[1];
  const void* batch = d_in[2];

  const long long nf = (long long)NN*D*3 + 3*PL + NG*D;
  const long long nu = (NN + 1) + NN + ET + (NG + 1) + 2;
  if (ws_size < (size_t)(nf + nu)*4 + 256) return;

  float* ws    = (float*)d_ws;
  float* xf    = ws;                               // NN*D (h buffer each layer)
  float* xl    = xf + (size_t)NN*D;
  float* xr    = xl + (size_t)NN*D;
  float* prm   = xr + (size_t)NN*D;                // 3*PL
  float* pool  = prm + 3*PL;                       // NG*D
  u32*  offs   = (u32*)(pool + NG*D);              // NN+1
  u32*  cursor = offs + (NN + 1);                  // NN
  u32*  csr    = cursor + NN;                      // ET
  u32*  bnd    = csr + ET;                         // NG+1
  int*  flags  = (int*)(bnd + (NG + 1));           // 2

  k_setup<<<169, 256, 0, stream>>>(ei, x, flags, cursor, pool);
  P18 ps;
  for (int i = 0; i < 18; ++i) ps.p[i] = d_in[3 + i];
  k_prep<<<20480 + 390, 256, 0, stream>>>(ps, x, xf, prm, flags);

  k_hist<<<ET/256, 256, 0, stream>>>(ei, cursor, flags);
  k_scan<<<2, 1024, 0, stream>>>(cursor, offs, batch, bnd, flags);
  k_scatter<<<ET/256, 256, 0, stream>>>(ei, cursor, csr, flags);

  for (int l = 0; l < 3; ++l){
    const float* p = prm + (size_t)l*PL;
    k_gemm<<<dim3(NN/128, 4), 256, 0, stream>>>(xf, p, xl, xr);
    k_node<<<NN/4, 256, 0, stream>>>(xl, xr, offs, csr, p, xf, d_out, flags, l == 2);
  }
  k_pool1<<<NG*64, 256, 0, stream>>>(xf, bnd, pool);
  k_pool2<<<8, 256, 0, stream>>>(pool, bnd, d_out, flags);
}

// Round 14
// 370.820 us; speedup vs baseline: 1.0925x; 1.0696x over previous
//
#include <hip/hip_runtime.h>

#define NN 40960
#define NE 655360
#define ET (NE + NN)        // 696320 edges incl self-loops
#define D 128
#define NG 16
#define PL 33280            // params per layer: WF[32768], bf[256], att[128], b[128]

typedef unsigned int u32;
typedef unsigned short u16;
typedef long long i64;

struct P18 { const void* p[18]; };

__device__ __forceinline__ float bf2f(u16 v){ return __uint_as_float(((u32)v)<<16); }
__device__ __forceinline__ u16 f2bf(float f){
  u32 u = __float_as_uint(f);
  return (u16)((u + 0x7FFFu + ((u>>16)&1u)) >> 16);
}
__device__ __forceinline__ int geti(const void* p, long long i, int f64, int bound){
  long long v = f64 ? ((const i64*)p)[i] : (long long)((const int*)p)[i];
  int x = (int)v;
  return (x < 0) ? 0 : ((x >= bound) ? bound-1 : x);
}
__device__ __forceinline__ void stf(void* p, long long i, float v, int isbf){
  if (isbf) ((u16*)p)[i] = f2bf(v); else ((float*)p)[i] = v;
}
__device__ __forceinline__ float rdf(const void* p, int i, int isbf){
  return isbf ? bf2f(((const u16*)p)[i]) : ((const float*)p)[i];
}
// load 4 consecutive floats (element offset foff, multiple of 4) from f32 or bf16 buffer
__device__ __forceinline__ float4 ld4(const void* p, size_t foff, int isbf){
  if (!isbf) return *(const float4*)((const float*)p + foff);
  ushort4 u = *(const ushort4*)((const u16*)p + foff);
  return make_float4(bf2f(u.x), bf2f(u.y), bf2f(u.z), bf2f(u.w));
}

// block 0: dtype detect; blocks 1..160: zero cursor; blocks 161..168: zero pool
__global__ void k_setup(const void* __restrict__ ei, const void* __restrict__ x,
                        int* __restrict__ flags, u32* __restrict__ cursor, float* __restrict__ pool){
  int b = blockIdx.x;
  if (b == 0){
    __shared__ int nz, cnt;
    if (threadIdx.x == 0){ nz = 0; cnt = 0; }
    __syncthreads();
    if (((const int*)ei)[2*threadIdx.x + 1] != 0) atomicAdd(&nz, 1);
    if (threadIdx.x < 128){
      u16 v = ((const u16*)x)[2*threadIdx.x];
      int ex = (v >> 7) & 0xFF;
      if (ex >= 100 && ex <= 140) atomicAdd(&cnt, 1);
    }
    __syncthreads();
    if (threadIdx.x == 0){
      flags[0] = (nz == 0) ? 1 : 0;
      flags[1] = (cnt >= 64) ? 1 : 0;
    }
  } else if (b <= 160){
    cursor[(b-1)*256 + threadIdx.x] = 0u;
  } else {
    int i = (b-161)*256 + threadIdx.x;
    if (i < NG*D) pool[i] = 0.f;
  }
}

// param pack only (130 blocks/layer)
__global__ void k_prep(P18 ps, float* __restrict__ prm, const int* __restrict__ flags){
  int b = blockIdx.x;
  int l = b / 130;
  int i = (b % 130)*256 + threadIdx.x;
  const void* Wl  = ps.p[6*l+0];
  const void* bl  = ps.p[6*l+1];
  const void* Wr  = ps.p[6*l+2];
  const void* br  = ps.p[6*l+3];
  const void* att = ps.p[6*l+4];
  const void* bb  = ps.p[6*l+5];
  int isbf = flags[1];
  float v;
  if (i < 32768){
    int k = i >> 8, gc = i & 255;
    v = (gc < 128) ? rdf(Wl, k*128 + gc, isbf) : rdf(Wr, k*128 + gc - 128, isbf);
  }
  else if (i < 33024){ int gc = i - 32768; v = (gc < 128) ? rdf(bl, gc, isbf) : rdf(br, gc - 128, isbf); }
  else if (i < 33152) v = rdf(att, i - 33024, isbf);
  else                v = rdf(bb, i - 33152, isbf);
  prm[(size_t)l*PL + i] = v;
}

// ---------- CSR build (by dst, self-loops appended); entry packs src|dst<<16 ----------
__global__ void k_hist(const void* __restrict__ ei, u32* __restrict__ cursor, const int* __restrict__ flags){
  int e = blockIdx.x*256 + threadIdx.x;
  if (e >= ET) return;
  int dd = (e < NE) ? geti(ei, (long long)NE + e, flags[0], NN) : e - NE;
  atomicAdd(&cursor[dd], 1u);
}

// 160 blocks: per-block sum of 256 cursor entries
__global__ __launch_bounds__(256) void k_scanA(const u32* __restrict__ cursor, u32* __restrict__ psum){
  __shared__ u32 red[256];
  int t = threadIdx.x;
  red[t] = cursor[blockIdx.x*256 + t];
  __syncthreads();
  #pragma unroll
  for (int off = 128; off > 0; off >>= 1){
    if (t < off) red[t] += red[t + off];
    __syncthreads();
  }
  if (t == 0) psum[blockIdx.x] = red[0];
}

// 1 block: exclusive scan of 160 partials (LDS), offs[NN]=total, graph bounds
__global__ __launch_bounds__(256) void k_scanB(u32* __restrict__ psum, u32* __restrict__ offs,
                                               const void* __restrict__ batch, u32* __restrict__ bnd,
                                               const int* __restrict__ flags){
  __shared__ u32 sh[256];
  int t = threadIdx.x;
  sh[t] = (t < 160) ? psum[t] : 0u;
  __syncthreads();
  #pragma unroll
  for (int off = 1; off < 256; off <<= 1){
    u32 add = (t >= off) ? sh[t - off] : 0u;
    __syncthreads();
    sh[t] += add;
    __syncthreads();
  }
  if (t < 160) psum[t] = (t == 0) ? 0u : sh[t - 1];
  if (t == 160) offs[NN] = sh[159];
  if (t >= 192 && t <= 192 + NG){
    int g = t - 192;
    if (g == NG){ bnd[NG] = NN; }
    else {
      int f = flags[0];
      int lo = 0, hi = NN;
      while (lo < hi){
        int mid = (lo + hi) >> 1;
        if (geti(batch, mid, f, NG) < g) lo = mid + 1; else hi = mid;
      }
      bnd[g] = (u32)lo;
    }
  }
}

// 160 blocks: local exclusive scan + base -> offs, cursor
__global__ __launch_bounds__(256) void k_scanC(u32* __restrict__ cursor, u32* __restrict__ offs,
                                               const u32* __restrict__ psum){
  __shared__ u32 sh[256];
  int t = threadIdx.x;
  int gi = blockIdx.x*256 + t;
  u32 v = cursor[gi];
  sh[t] = v;
  __syncthreads();
  #pragma unroll
  for (int off = 1; off < 256; off <<= 1){
    u32 add = (t >= off) ? sh[t - off] : 0u;
    __syncthreads();
    sh[t] += add;
    __syncthreads();
  }
  u32 excl = ((t > 0) ? sh[t - 1] : 0u) + psum[blockIdx.x];
  offs[gi] = excl;
  cursor[gi] = excl;
}

__global__ void k_scatter(const void* __restrict__ ei, u32* __restrict__ cursor,
                          u32* __restrict__ csr, const int* __restrict__ flags){
  int e = blockIdx.x*256 + threadIdx.x;
  if (e >= ET) return;
  int f = flags[0];
  int s, dd;
  if (e < NE){ s = geti(ei, e, f, NN); dd = geti(ei, (long long)NE + e, f, NN); }
  else { s = dd = e - NE; }
  u32 pos = atomicAdd(&cursor[dd], 1u);
  csr[pos] = (u32)s | ((u32)dd << 16);
}

// ---------- GEMM: 128 rows x 128 cols per block, BK=32 x 4 tiles, 8x8 quadrant microtile ----------
// Per k: 64 FMA vs 4 ds_read_b128 (128 vs ~48 issue-cyc). LDS 32KB -> 4 blocks/CU.
// Xs stage-writes 2-way via XOR swizzle; reads broadcast/2-way. Layer 0 reads input directly.
__global__ __launch_bounds__(256, 4) void k_gemm(const void* __restrict__ Xv, const float* __restrict__ pr,
                                                 float* __restrict__ xl, float* __restrict__ xr,
                                                 const int* __restrict__ flags, int lay0)
{
  __shared__ float Xs[32][128];   // [k][row], row XOR-swizzled
  __shared__ float Ws[32][128];   // [k][col]
  int tid = threadIdx.x;
  int row0 = blockIdx.x * 128;
  int bc0  = blockIdx.y * 128;    // 0 -> xl, 128 -> xr
  int ty = tid >> 4, tx = tid & 15;
  int r = ty*4, c = tx*4;
  int isbf = lay0 ? flags[1] : 0;

  float4 bv0 = *(const float4*)(pr + 32768 + bc0 + c);
  float4 bv1 = *(const float4*)(pr + 32768 + bc0 + c + 64);
  float acc[2][2][4][4];
  #pragma unroll
  for (int qr = 0; qr < 2; ++qr)
    #pragma unroll
    for (int i = 0; i < 4; ++i){
      acc[qr][0][i][0] = bv0.x; acc[qr][0][i][1] = bv0.y;
      acc[qr][0][i][2] = bv0.z; acc[qr][0][i][3] = bv0.w;
      acc[qr][1][i][0] = bv1.x; acc[qr][1][i][1] = bv1.y;
      acc[qr][1][i][2] = bv1.z; acc[qr][1][i][3] = bv1.w;
    }

  #pragma unroll
  for (int kt = 0; kt < 4; ++kt){
    // stage X: 128 rows x 32 k (1024 float4s)
    #pragma unroll
    for (int i = 0; i < 4; ++i){
      int idx = tid + i*256;
      int row = idx >> 3, k4 = idx & 7;
      float4 v = ld4(Xv, (size_t)(row0 + row)*D + kt*32 + k4*4, isbf);
      int rs = row ^ (k4 << 2);
      Xs[k4*4+0][rs] = v.x;
      Xs[k4*4+1][rs] = v.y;
      Xs[k4*4+2][rs] = v.z;
      Xs[k4*4+3][rs] = v.w;
    }
    // stage W: 32 k x 128 cols (1024 float4s)
    const float* Wb = pr + (size_t)kt*32*256 + bc0;
    #pragma unroll
    for (int i = 0; i < 4; ++i){
      int idx = tid + i*256;
      int k = idx >> 5, c4 = idx & 31;
      *(float4*)&Ws[k][c4*4] = *(const float4*)(Wb + (size_t)k*256 + c4*4);
    }
    __syncthreads();
    #pragma unroll 4
    for (int k = 0; k < 32; ++k){
      int swb = ((k >> 2) & 7) << 2;
      int ra = r ^ swb;
      float4 a0 = *(const float4*)&Xs[k][ra];
      float4 a1 = *(const float4*)&Xs[k][ra + 64];
      float4 w0 = *(const float4*)&Ws[k][c];
      float4 w1 = *(const float4*)&Ws[k][c + 64];
      #pragma unroll
      for (int qr = 0; qr < 2; ++qr){
        float ax = qr ? a1.x : a0.x, ay = qr ? a1.y : a0.y;
        float az = qr ? a1.z : a0.z, aw = qr ? a1.w : a0.w;
        #pragma unroll
        for (int qc = 0; qc < 2; ++qc){
          float wx = qc ? w1.x : w0.x, wy = qc ? w1.y : w0.y;
          float wz = qc ? w1.z : w0.z, ww = qc ? w1.w : w0.w;
          acc[qr][qc][0][0] = fmaf(ax, wx, acc[qr][qc][0][0]);
          acc[qr][qc][0][1] = fmaf(ax, wy, acc[qr][qc][0][1]);
          acc[qr][qc][0][2] = fmaf(ax, wz, acc[qr][qc][0][2]);
          acc[qr][qc][0][3] = fmaf(ax, ww, acc[qr][qc][0][3]);
          acc[qr][qc][1][0] = fmaf(ay, wx, acc[qr][qc][1][0]);
          acc[qr][qc][1][1] = fmaf(ay, wy, acc[qr][qc][1][1]);
          acc[qr][qc][1][2] = fmaf(ay, wz, acc[qr][qc][1][2]);
          acc[qr][qc][1][3] = fmaf(ay, ww, acc[qr][qc][1][3]);
          acc[qr][qc][2][0] = fmaf(az, wx, acc[qr][qc][2][0]);
          acc[qr][qc][2][1] = fmaf(az, wy, acc[qr][qc][2][1]);
          acc[qr][qc][2][2] = fmaf(az, wz, acc[qr][qc][2][2]);
          acc[qr][qc][2][3] = fmaf(az, ww, acc[qr][qc][2][3]);
          acc[qr][qc][3][0] = fmaf(aw, wx, acc[qr][qc][3][0]);
          acc[qr][qc][3][1] = fmaf(aw, wy, acc[qr][qc][3][1]);
          acc[qr][qc][3][2] = fmaf(aw, wz, acc[qr][qc][3][2]);
          acc[qr][qc][3][3] = fmaf(aw, ww, acc[qr][qc][3][3]);
        }
      }
    }
    __syncthreads();
  }

  float* base = bc0 ? xr : xl;
  #pragma unroll
  for (int qr = 0; qr < 2; ++qr)
    #pragma unroll
    for (int i = 0; i < 4; ++i){
      int grow = row0 + qr*64 + r + i;
      *(float4*)(base + (size_t)grow*D + c) =
          make_float4(acc[qr][0][i][0], acc[qr][0][i][1], acc[qr][0][i][2], acc[qr][0][i][3]);
      *(float4*)(base + (size_t)grow*D + c + 64) =
          make_float4(acc[qr][1][i][0], acc[qr][1][i][1], acc[qr][1][i][2], acc[qr][1][i][3]);
    }
}

// ---------- fused per-node attention: wave/node, depth-2 pipelined gather, defer-max ----------
__global__ __launch_bounds__(256) void k_node(const float* __restrict__ xl, const float* __restrict__ xr,
    const u32* __restrict__ offs, const u32* __restrict__ csr, const float* __restrict__ pr,
    float* __restrict__ hnew, void* __restrict__ out, const int* __restrict__ flags, int last)
{
  int node = blockIdx.x*4 + (threadIdx.x >> 6);
  int lane = threadIdx.x & 63;
  int half = lane >> 5;
  int c = (lane & 31) * 4;
  float4 xrv  = *(const float4*)(xr + (size_t)node*D + c);
  float4 attv = *(const float4*)(pr + 33024 + c);
  u32 j0 = offs[node], j1 = offs[node + 1];

  float mx = -1e30f, ssum = 0.f;
  float4 acc = make_float4(0.f, 0.f, 0.f, 0.f);

  #define SRCJ(jj) ((int)(csr[(jj) < j1 ? (jj) : j0] & 0xFFFFu))
  u32 j = j0 + half;
  int s0 = SRCJ(j), s1 = SRCJ(j+2);
  float4 g0 = *(const float4*)(xl + (size_t)s0*D + c);
  float4 g1 = *(const float4*)(xl + (size_t)s1*D + c);
  int s2 = SRCJ(j+4), s3 = SRCJ(j+6);

  for (; j < j1; j += 4){
    float4 n0 = *(const float4*)(xl + (size_t)s2*D + c);
    float4 n1 = *(const float4*)(xl + (size_t)s3*D + c);
    int t0 = SRCJ(j+8), t1 = SRCJ(j+10);

    {
      float m, p;
      m = g0.x + xrv.x; p = fmaxf(m, 0.2f*m) * attv.x;
      m = g0.y + xrv.y; p = fmaf(fmaxf(m, 0.2f*m), attv.y, p);
      m = g0.z + xrv.z; p = fmaf(fmaxf(m, 0.2f*m), attv.z, p);
      m = g0.w + xrv.w; p = fmaf(fmaxf(m, 0.2f*m), attv.w, p);
      p += __shfl_xor(p, 1, 64);
      p += __shfl_xor(p, 2, 64);
      p += __shfl_xor(p, 4, 64);
      if (p > mx + 8.f){
        float eo = __expf(mx - p);
        ssum  *= eo;
        acc.x *= eo; acc.y *= eo; acc.z *= eo; acc.w *= eo;
        mx = p;
      }
      float en = __expf(p - mx);
      ssum += en;
      acc.x = fmaf(en, g0.x, acc.x);
      acc.y = fmaf(en, g0.y, acc.y);
      acc.z = fmaf(en, g0.z, acc.z);
      acc.w = fmaf(en, g0.w, acc.w);
    }
    if (j + 2 < j1){
      float m, p;
      m = g1.x + xrv.x; p = fmaxf(m, 0.2f*m) * attv.x;
      m = g1.y + xrv.y; p = fmaf(fmaxf(m, 0.2f*m), attv.y, p);
      m = g1.z + xrv.z; p = fmaf(fmaxf(m, 0.2f*m), attv.z, p);
      m = g1.w + xrv.w; p = fmaf(fmaxf(m, 0.2f*m), attv.w, p);
      p += __shfl_xor(p, 1, 64);
      p += __shfl_xor(p, 2, 64);
      p += __shfl_xor(p, 4, 64);
      if (p > mx + 8.f){
        float eo = __expf(mx - p);
        ssum  *= eo;
        acc.x *= eo; acc.y *= eo; acc.z *= eo; acc.w *= eo;
        mx = p;
      }
      float en = __expf(p - mx);
      ssum += en;
      acc.x = fmaf(en, g1.x, acc.x);
      acc.y = fmaf(en, g1.y, acc.y);
      acc.z = fmaf(en, g1.z, acc.z);
      acc.w = fmaf(en, g1.w, acc.w);
    }
    g0 = n0; g1 = n1; s2 = t0; s3 = t1;
  }
  #undef SRCJ

  float mo = __shfl_xor(mx, 32, 64);
  float so = __shfl_xor(ssum, 32, 64);
  float ax = __shfl_xor(acc.x, 32, 64);
  float ay = __shfl_xor(acc.y, 32, 64);
  float az = __shfl_xor(acc.z, 32, 64);
  float aw = __shfl_xor(acc.w, 32, 64);
  float n  = fmaxf(mx, mo);
  float e0 = __expf(mx - n), e1 = __expf(mo - n);
  ssum  = ssum*e0 + so*e1;
  acc.x = acc.x*e0 + ax*e1;
  acc.y = acc.y*e0 + ay*e1;
  acc.z = acc.z*e0 + az*e1;
  acc.w = acc.w*e0 + aw*e1;

  if (half == 0){
    float inv = 1.0f / fmaxf(ssum, 1e-30f);
    float4 bv = *(const float4*)(pr + 33152 + c);
    float4 v = make_float4(acc.x*inv + bv.x, acc.y*inv + bv.y,
                           acc.z*inv + bv.z, acc.w*inv + bv.w);
    if (!last){
      v.x = fmaxf(v.x, 0.f); v.y = fmaxf(v.y, 0.f);
      v.z = fmaxf(v.z, 0.f); v.w = fmaxf(v.w, 0.f);
      *(float4*)(hnew + (size_t)node*D + c) = v;
    } else {
      *(float4*)(hnew + (size_t)node*D + c) = v;
      int isbf = flags[1];
      long long o = (long long)NG*D + (long long)node*D + c;
      stf(out, o+0, v.x, isbf); stf(out, o+1, v.y, isbf);
      stf(out, o+2, v.z, isbf); stf(out, o+3, v.w, isbf);
    }
  }
}

// ---------- two-stage mean pool ----------
__global__ __launch_bounds__(256) void k_pool1(const float* __restrict__ h, const u32* __restrict__ bnd,
                                               float* __restrict__ pool){
  int g = blockIdx.x >> 6, sl = blockIdx.x & 63;
  int ch = threadIdx.x & 127, ro = threadIdx.x >> 7;
  u32 b0 = bnd[g], b1 = bnd[g + 1];
  float acc = 0.f;
  for (u32 r = b0 + sl*2 + ro; r < b1; r += 128) acc += h[(size_t)r*D + ch];
  unsafeAtomicAdd(&pool[g*D + ch], acc);
}

__global__ void k_pool2(const float* __restrict__ pool, const u32* __restrict__ bnd,
                        void* __restrict__ out, const int* __restrict__ flags){
  int i = blockIdx.x*256 + threadIdx.x;
  if (i >= NG*D) return;
  int g = i >> 7;
  float c = (float)(bnd[g + 1] - bnd[g]);
  stf(out, i, pool[i] / fmaxf(c, 1.f), flags[1]);
}

extern "C" void kernel_launch(void* const* d_in, const int* in_sizes, int n_in,
                              void* d_out, int out_size, void* d_ws, size_t ws_size,
                              hipStream_t stream) {
  const void* x     = d_in[0];
  const void* ei    = d_in[1];
  const void* batch = d_in[2];

  const long long nf = (long long)NN*D*3 + 3*PL + NG*D;
  const long long nu = (NN + 1) + NN + ET + (NG + 1) + 2 + 160;
  if (ws_size < (size_t)(nf + nu)*4 + 256) return;

  float* ws    = (float*)d_ws;
  float* xf    = ws;                               // NN*D (h buffer each layer)
  float* xl    = xf + (size_t)NN*D;
  float* xr    = xl + (size_t)NN*D;
  float* prm   = xr + (size_t)NN*D;                // 3*PL
  float* pool  = prm + 3*PL;                       // NG*D
  u32*  offs   = (u32*)(pool + NG*D);              // NN+1
  u32*  cursor = offs + (NN + 1);                  // NN
  u32*  csr    = cursor + NN;                      // ET
  u32*  bnd    = csr + ET;                         // NG+1
  u32*  psum   = bnd + (NG + 1);                   // 160
  int*  flags  = (int*)(psum + 160);               // 2

  k_setup<<<169, 256, 0, stream>>>(ei, x, flags, cursor, pool);
  P18 ps;
  for (int i = 0; i < 18; ++i) ps.p[i] = d_in[3 + i];
  k_prep<<<390, 256, 0, stream>>>(ps, prm, flags);

  k_hist<<<ET/256, 256, 0, stream>>>(ei, cursor, flags);
  k_scanA<<<160, 256, 0, stream>>>(cursor, psum);
  k_scanB<<<1, 256, 0, stream>>>(psum, offs, batch, bnd, flags);
  k_scanC<<<160, 256, 0, stream>>>(cursor, offs, psum);
  k_scatter<<<ET/256, 256, 0, stream>>>(ei, cursor, csr, flags);

  for (int l = 0; l < 3; ++l){
    const float* p = prm + (size_t)l*PL;
    const void* Xin = (l == 0) ? x : (const void*)xf;
    k_gemm<<<dim3(NN/128, 2), 256, 0, stream>>>(Xin, p, xl, xr, flags, l == 0);
    k_node<<<NN/4, 256, 0, stream>>>(xl, xr, offs, csr, p, xf, d_out, flags, l == 2);
  }
  k_pool1<<<NG*64, 256, 0, stream>>>(xf, bnd, pool);
  k_pool2<<<8, 256, 0, stream>>>(pool, bnd, d_out, flags);
}

// Round 15
// 339.405 us; speedup vs baseline: 1.1936x; 1.0926x over previous
//
#include <hip/hip_runtime.h>

#define NN 40960
#define NE 655360
#define ET (NE + NN)        // 696320 edges incl self-loops
#define D 128
#define NG 16
#define PL 33280            // params per layer: WF[32768], bf[256], att[128], b[128]

typedef unsigned int u32;
typedef unsigned short u16;
typedef long long i64;

struct P18 { const void* p[18]; };

__device__ __forceinline__ float bf2f(u16 v){ return __uint_as_float(((u32)v)<<16); }
__device__ __forceinline__ u16 f2bf(float f){
  u32 u = __float_as_uint(f);
  return (u16)((u + 0x7FFFu + ((u>>16)&1u)) >> 16);
}
__device__ __forceinline__ int geti(const void* p, long long i, int f64, int bound){
  long long v = f64 ? ((const i64*)p)[i] : (long long)((const int*)p)[i];
  int x = (int)v;
  return (x < 0) ? 0 : ((x >= bound) ? bound-1 : x);
}
__device__ __forceinline__ void stf(void* p, long long i, float v, int isbf){
  if (isbf) ((u16*)p)[i] = f2bf(v); else ((float*)p)[i] = v;
}
__device__ __forceinline__ float rdf(const void* p, int i, int isbf){
  return isbf ? bf2f(((const u16*)p)[i]) : ((const float*)p)[i];
}
// load 4 consecutive floats (element offset foff, multiple of 4) from f32 or bf16 buffer
__device__ __forceinline__ float4 ld4(const void* p, size_t foff, int isbf){
  if (!isbf) return *(const float4*)((const float*)p + foff);
  ushort4 u = *(const ushort4*)((const u16*)p + foff);
  return make_float4(bf2f(u.x), bf2f(u.y), bf2f(u.z), bf2f(u.w));
}
// bf16x4 load (8 B) -> 4 floats
__device__ __forceinline__ float4 ldb4(const u16* p){
  ushort4 u = *(const ushort4*)p;
  return make_float4(bf2f(u.x), bf2f(u.y), bf2f(u.z), bf2f(u.w));
}

// block 0: dtype detect; blocks 1..160: zero cursor; blocks 161..168: zero pool
__global__ void k_setup(const void* __restrict__ ei, const void* __restrict__ x,
                        int* __restrict__ flags, u32* __restrict__ cursor, float* __restrict__ pool){
  int b = blockIdx.x;
  if (b == 0){
    __shared__ int nz, cnt;
    if (threadIdx.x == 0){ nz = 0; cnt = 0; }
    __syncthreads();
    if (((const int*)ei)[2*threadIdx.x + 1] != 0) atomicAdd(&nz, 1);
    if (threadIdx.x < 128){
      u16 v = ((const u16*)x)[2*threadIdx.x];
      int ex = (v >> 7) & 0xFF;
      if (ex >= 100 && ex <= 140) atomicAdd(&cnt, 1);
    }
    __syncthreads();
    if (threadIdx.x == 0){
      flags[0] = (nz == 0) ? 1 : 0;
      flags[1] = (cnt >= 64) ? 1 : 0;
    }
  } else if (b <= 160){
    cursor[(b-1)*256 + threadIdx.x] = 0u;
  } else {
    int i = (b-161)*256 + threadIdx.x;
    if (i < NG*D) pool[i] = 0.f;
  }
}

// param pack only (130 blocks/layer)
__global__ void k_prep(P18 ps, float* __restrict__ prm, const int* __restrict__ flags){
  int b = blockIdx.x;
  int l = b / 130;
  int i = (b % 130)*256 + threadIdx.x;
  const void* Wl  = ps.p[6*l+0];
  const void* bl  = ps.p[6*l+1];
  const void* Wr  = ps.p[6*l+2];
  const void* br  = ps.p[6*l+3];
  const void* att = ps.p[6*l+4];
  const void* bb  = ps.p[6*l+5];
  int isbf = flags[1];
  float v;
  if (i < 32768){
    int k = i >> 8, gc = i & 255;
    v = (gc < 128) ? rdf(Wl, k*128 + gc, isbf) : rdf(Wr, k*128 + gc - 128, isbf);
  }
  else if (i < 33024){ int gc = i - 32768; v = (gc < 128) ? rdf(bl, gc, isbf) : rdf(br, gc - 128, isbf); }
  else if (i < 33152) v = rdf(att, i - 33024, isbf);
  else                v = rdf(bb, i - 33152, isbf);
  prm[(size_t)l*PL + i] = v;
}

// ---------- CSR build (by dst, self-loops appended); entry packs src|dst<<16 ----------
__global__ void k_hist(const void* __restrict__ ei, u32* __restrict__ cursor, const int* __restrict__ flags){
  int e = blockIdx.x*256 + threadIdx.x;
  if (e >= ET) return;
  int dd = (e < NE) ? geti(ei, (long long)NE + e, flags[0], NN) : e - NE;
  atomicAdd(&cursor[dd], 1u);
}

// 160 blocks: per-block sum of 256 cursor entries
__global__ __launch_bounds__(256) void k_scanA(const u32* __restrict__ cursor, u32* __restrict__ psum){
  __shared__ u32 red[256];
  int t = threadIdx.x;
  red[t] = cursor[blockIdx.x*256 + t];
  __syncthreads();
  #pragma unroll
  for (int off = 128; off > 0; off >>= 1){
    if (t < off) red[t] += red[t + off];
    __syncthreads();
  }
  if (t == 0) psum[blockIdx.x] = red[0];
}

// 1 block: exclusive scan of 160 partials (LDS), offs[NN]=total, graph bounds
__global__ __launch_bounds__(256) void k_scanB(u32* __restrict__ psum, u32* __restrict__ offs,
                                               const void* __restrict__ batch, u32* __restrict__ bnd,
                                               const int* __restrict__ flags){
  __shared__ u32 sh[256];
  int t = threadIdx.x;
  sh[t] = (t < 160) ? psum[t] : 0u;
  __syncthreads();
  #pragma unroll
  for (int off = 1; off < 256; off <<= 1){
    u32 add = (t >= off) ? sh[t - off] : 0u;
    __syncthreads();
    sh[t] += add;
    __syncthreads();
  }
  if (t < 160) psum[t] = (t == 0) ? 0u : sh[t - 1];
  if (t == 160) offs[NN] = sh[159];
  if (t >= 192 && t <= 192 + NG){
    int g = t - 192;
    if (g == NG){ bnd[NG] = NN; }
    else {
      int f = flags[0];
      int lo = 0, hi = NN;
      while (lo < hi){
        int mid = (lo + hi) >> 1;
        if (geti(batch, mid, f, NG) < g) lo = mid + 1; else hi = mid;
      }
      bnd[g] = (u32)lo;
    }
  }
}

// 160 blocks: local exclusive scan + base -> offs, cursor
__global__ __launch_bounds__(256) void k_scanC(u32* __restrict__ cursor, u32* __restrict__ offs,
                                               const u32* __restrict__ psum){
  __shared__ u32 sh[256];
  int t = threadIdx.x;
  int gi = blockIdx.x*256 + t;
  u32 v = cursor[gi];
  sh[t] = v;
  __syncthreads();
  #pragma unroll
  for (int off = 1; off < 256; off <<= 1){
    u32 add = (t >= off) ? sh[t - off] : 0u;
    __syncthreads();
    sh[t] += add;
    __syncthreads();
  }
  u32 excl = ((t > 0) ? sh[t - 1] : 0u) + psum[blockIdx.x];
  offs[gi] = excl;
  cursor[gi] = excl;
}

__global__ void k_scatter(const void* __restrict__ ei, u32* __restrict__ cursor,
                          u32* __restrict__ csr, const int* __restrict__ flags){
  int e = blockIdx.x*256 + threadIdx.x;
  if (e >= ET) return;
  int f = flags[0];
  int s, dd;
  if (e < NE){ s = geti(ei, e, f, NN); dd = geti(ei, (long long)NE + e, f, NN); }
  else { s = dd = e - NE; }
  u32 pos = atomicAdd(&cursor[dd], 1u);
  csr[pos] = (u32)s | ((u32)dd << 16);
}

// ---------- GEMM: 128x128 tile, BK=32 x 4, 8x8 quadrant microtile; OUTPUT bf16 ----------
__global__ __launch_bounds__(256, 4) void k_gemm(const void* __restrict__ Xv, const float* __restrict__ pr,
                                                 u16* __restrict__ xl, u16* __restrict__ xr,
                                                 const int* __restrict__ flags, int lay0)
{
  __shared__ float Xs[32][128];   // [k][row], row XOR-swizzled
  __shared__ float Ws[32][128];   // [k][col]
  int tid = threadIdx.x;
  int row0 = blockIdx.x * 128;
  int bc0  = blockIdx.y * 128;    // 0 -> xl, 128 -> xr
  int ty = tid >> 4, tx = tid & 15;
  int r = ty*4, c = tx*4;
  int isbf = lay0 ? flags[1] : 0;

  float4 bv0 = *(const float4*)(pr + 32768 + bc0 + c);
  float4 bv1 = *(const float4*)(pr + 32768 + bc0 + c + 64);
  float acc[2][2][4][4];
  #pragma unroll
  for (int qr = 0; qr < 2; ++qr)
    #pragma unroll
    for (int i = 0; i < 4; ++i){
      acc[qr][0][i][0] = bv0.x; acc[qr][0][i][1] = bv0.y;
      acc[qr][0][i][2] = bv0.z; acc[qr][0][i][3] = bv0.w;
      acc[qr][1][i][0] = bv1.x; acc[qr][1][i][1] = bv1.y;
      acc[qr][1][i][2] = bv1.z; acc[qr][1][i][3] = bv1.w;
    }

  #pragma unroll
  for (int kt = 0; kt < 4; ++kt){
    #pragma unroll
    for (int i = 0; i < 4; ++i){
      int idx = tid + i*256;
      int row = idx >> 3, k4 = idx & 7;
      float4 v = ld4(Xv, (size_t)(row0 + row)*D + kt*32 + k4*4, isbf);
      int rs = row ^ (k4 << 2);
      Xs[k4*4+0][rs] = v.x;
      Xs[k4*4+1][rs] = v.y;
      Xs[k4*4+2][rs] = v.z;
      Xs[k4*4+3][rs] = v.w;
    }
    const float* Wb = pr + (size_t)kt*32*256 + bc0;
    #pragma unroll
    for (int i = 0; i < 4; ++i){
      int idx = tid + i*256;
      int k = idx >> 5, c4 = idx & 31;
      *(float4*)&Ws[k][c4*4] = *(const float4*)(Wb + (size_t)k*256 + c4*4);
    }
    __syncthreads();
    #pragma unroll 4
    for (int k = 0; k < 32; ++k){
      int swb = ((k >> 2) & 7) << 2;
      int ra = r ^ swb;
      float4 a0 = *(const float4*)&Xs[k][ra];
      float4 a1 = *(const float4*)&Xs[k][ra + 64];
      float4 w0 = *(const float4*)&Ws[k][c];
      float4 w1 = *(const float4*)&Ws[k][c + 64];
      #pragma unroll
      for (int qr = 0; qr < 2; ++qr){
        float ax = qr ? a1.x : a0.x, ay = qr ? a1.y : a0.y;
        float az = qr ? a1.z : a0.z, aw = qr ? a1.w : a0.w;
        #pragma unroll
        for (int qc = 0; qc < 2; ++qc){
          float wx = qc ? w1.x : w0.x, wy = qc ? w1.y : w0.y;
          float wz = qc ? w1.z : w0.z, ww = qc ? w1.w : w0.w;
          acc[qr][qc][0][0] = fmaf(ax, wx, acc[qr][qc][0][0]);
          acc[qr][qc][0][1] = fmaf(ax, wy, acc[qr][qc][0][1]);
          acc[qr][qc][0][2] = fmaf(ax, wz, acc[qr][qc][0][2]);
          acc[qr][qc][0][3] = fmaf(ax, ww, acc[qr][qc][0][3]);
          acc[qr][qc][1][0] = fmaf(ay, wx, acc[qr][qc][1][0]);
          acc[qr][qc][1][1] = fmaf(ay, wy, acc[qr][qc][1][1]);
          acc[qr][qc][1][2] = fmaf(ay, wz, acc[qr][qc][1][2]);
          acc[qr][qc][1][3] = fmaf(ay, ww, acc[qr][qc][1][3]);
          acc[qr][qc][2][0] = fmaf(az, wx, acc[qr][qc][2][0]);
          acc[qr][qc][2][1] = fmaf(az, wy, acc[qr][qc][2][1]);
          acc[qr][qc][2][2] = fmaf(az, wz, acc[qr][qc][2][2]);
          acc[qr][qc][2][3] = fmaf(az, ww, acc[qr][qc][2][3]);
          acc[qr][qc][3][0] = fmaf(aw, wx, acc[qr][qc][3][0]);
          acc[qr][qc][3][1] = fmaf(aw, wy, acc[qr][qc][3][1]);
          acc[qr][qc][3][2] = fmaf(aw, wz, acc[qr][qc][3][2]);
          acc[qr][qc][3][3] = fmaf(aw, ww, acc[qr][qc][3][3]);
        }
      }
    }
    __syncthreads();
  }

  u16* base = bc0 ? xr : xl;
  #pragma unroll
  for (int qr = 0; qr < 2; ++qr)
    #pragma unroll
    for (int i = 0; i < 4; ++i){
      int grow = row0 + qr*64 + r + i;
      ushort4 o0 = make_ushort4(f2bf(acc[qr][0][i][0]), f2bf(acc[qr][0][i][1]),
                                f2bf(acc[qr][0][i][2]), f2bf(acc[qr][0][i][3]));
      ushort4 o1 = make_ushort4(f2bf(acc[qr][1][i][0]), f2bf(acc[qr][1][i][1]),
                                f2bf(acc[qr][1][i][2]), f2bf(acc[qr][1][i][3]));
      *(ushort4*)(base + (size_t)grow*D + c) = o0;
      *(ushort4*)(base + (size_t)grow*D + c + 64) = o1;
    }
}

// ---------- fused per-node attention: bf16 gather (halved bytes), depth-2 pipeline ----------
__global__ __launch_bounds__(256) void k_node(const u16* __restrict__ xl, const u16* __restrict__ xr,
    const u32* __restrict__ offs, const u32* __restrict__ csr, const float* __restrict__ pr,
    float* __restrict__ hnew, void* __restrict__ out, const int* __restrict__ flags, int last)
{
  int node = blockIdx.x*4 + (threadIdx.x >> 6);
  int lane = threadIdx.x & 63;
  int half = lane >> 5;
  int c = (lane & 31) * 4;
  float4 xrv  = ldb4(xr + (size_t)node*D + c);
  float4 attv = *(const float4*)(pr + 33024 + c);
  u32 j0 = offs[node], j1 = offs[node + 1];

  float mx = -1e30f, ssum = 0.f;
  float4 acc = make_float4(0.f, 0.f, 0.f, 0.f);

  #define SRCJ(jj) ((int)(csr[(jj) < j1 ? (jj) : j0] & 0xFFFFu))
  u32 j = j0 + half;
  int s0 = SRCJ(j), s1 = SRCJ(j+2);
  float4 g0 = ldb4(xl + (size_t)s0*D + c);
  float4 g1 = ldb4(xl + (size_t)s1*D + c);
  int s2 = SRCJ(j+4), s3 = SRCJ(j+6);

  for (; j < j1; j += 4){
    float4 n0 = ldb4(xl + (size_t)s2*D + c);
    float4 n1 = ldb4(xl + (size_t)s3*D + c);
    int t0 = SRCJ(j+8), t1 = SRCJ(j+10);

    {
      float m, p;
      m = g0.x + xrv.x; p = fmaxf(m, 0.2f*m) * attv.x;
      m = g0.y + xrv.y; p = fmaf(fmaxf(m, 0.2f*m), attv.y, p);
      m = g0.z + xrv.z; p = fmaf(fmaxf(m, 0.2f*m), attv.z, p);
      m = g0.w + xrv.w; p = fmaf(fmaxf(m, 0.2f*m), attv.w, p);
      p += __shfl_xor(p, 1, 64);
      p += __shfl_xor(p, 2, 64);
      p += __shfl_xor(p, 4, 64);
      if (p > mx + 8.f){
        float eo = __expf(mx - p);
        ssum  *= eo;
        acc.x *= eo; acc.y *= eo; acc.z *= eo; acc.w *= eo;
        mx = p;
      }
      float en = __expf(p - mx);
      ssum += en;
      acc.x = fmaf(en, g0.x, acc.x);
      acc.y = fmaf(en, g0.y, acc.y);
      acc.z = fmaf(en, g0.z, acc.z);
      acc.w = fmaf(en, g0.w, acc.w);
    }
    if (j + 2 < j1){
      float m, p;
      m = g1.x + xrv.x; p = fmaxf(m, 0.2f*m) * attv.x;
      m = g1.y + xrv.y; p = fmaf(fmaxf(m, 0.2f*m), attv.y, p);
      m = g1.z + xrv.z; p = fmaf(fmaxf(m, 0.2f*m), attv.z, p);
      m = g1.w + xrv.w; p = fmaf(fmaxf(m, 0.2f*m), attv.w, p);
      p += __shfl_xor(p, 1, 64);
      p += __shfl_xor(p, 2, 64);
      p += __shfl_xor(p, 4, 64);
      if (p > mx + 8.f){
        float eo = __expf(mx - p);
        ssum  *= eo;
        acc.x *= eo; acc.y *= eo; acc.z *= eo; acc.w *= eo;
        mx = p;
      }
      float en = __expf(p - mx);
      ssum += en;
      acc.x = fmaf(en, g1.x, acc.x);
      acc.y = fmaf(en, g1.y, acc.y);
      acc.z = fmaf(en, g1.z, acc.z);
      acc.w = fmaf(en, g1.w, acc.w);
    }
    g0 = n0; g1 = n1; s2 = t0; s3 = t1;
  }
  #undef SRCJ

  float mo = __shfl_xor(mx, 32, 64);
  float so = __shfl_xor(ssum, 32, 64);
  float ax = __shfl_xor(acc.x, 32, 64);
  float ay = __shfl_xor(acc.y, 32, 64);
  float az = __shfl_xor(acc.z, 32, 64);
  float aw = __shfl_xor(acc.w, 32, 64);
  float n  = fmaxf(mx, mo);
  float e0 = __expf(mx - n), e1 = __expf(mo - n);
  ssum  = ssum*e0 + so*e1;
  acc.x = acc.x*e0 + ax*e1;
  acc.y = acc.y*e0 + ay*e1;
  acc.z = acc.z*e0 + az*e1;
  acc.w = acc.w*e0 + aw*e1;

  if (half == 0){
    float inv = 1.0f / fmaxf(ssum, 1e-30f);
    float4 bv = *(const float4*)(pr + 33152 + c);
    float4 v = make_float4(acc.x*inv + bv.x, acc.y*inv + bv.y,
                           acc.z*inv + bv.z, acc.w*inv + bv.w);
    if (!last){
      v.x = fmaxf(v.x, 0.f); v.y = fmaxf(v.y, 0.f);
      v.z = fmaxf(v.z, 0.f); v.w = fmaxf(v.w, 0.f);
      *(float4*)(hnew + (size_t)node*D + c) = v;
    } else {
      *(float4*)(hnew + (size_t)node*D + c) = v;
      int isbf = flags[1];
      long long o = (long long)NG*D + (long long)node*D + c;
      stf(out, o+0, v.x, isbf); stf(out, o+1, v.y, isbf);
      stf(out, o+2, v.z, isbf); stf(out, o+3, v.w, isbf);
    }
  }
}

// ---------- two-stage mean pool ----------
__global__ __launch_bounds__(256) void k_pool1(const float* __restrict__ h, const u32* __restrict__ bnd,
                                               float* __restrict__ pool){
  int g = blockIdx.x >> 6, sl = blockIdx.x & 63;
  int ch = threadIdx.x & 127, ro = threadIdx.x >> 7;
  u32 b0 = bnd[g], b1 = bnd[g + 1];
  float acc = 0.f;
  for (u32 r = b0 + sl*2 + ro; r < b1; r += 128) acc += h[(size_t)r*D + ch];
  unsafeAtomicAdd(&pool[g*D + ch], acc);
}

__global__ void k_pool2(const float* __restrict__ pool, const u32* __restrict__ bnd,
                        void* __restrict__ out, const int* __restrict__ flags){
  int i = blockIdx.x*256 + threadIdx.x;
  if (i >= NG*D) return;
  int g = i >> 7;
  float c = (float)(bnd[g + 1] - bnd[g]);
  stf(out, i, pool[i] / fmaxf(c, 1.f), flags[1]);
}

extern "C" void kernel_launch(void* const* d_in, const int* in_sizes, int n_in,
                              void* d_out, int out_size, void* d_ws, size_t ws_size,
                              hipStream_t stream) {
  const void* x     = d_in[0];
  const void* ei    = d_in[1];
  const void* batch = d_in[2];

  const long long nf = (long long)NN*D*3 + 3*PL + NG*D;
  const long long nu = (NN + 1) + NN + ET + (NG + 1) + 2 + 160;
  if (ws_size < (size_t)(nf + nu)*4 + 256) return;

  float* ws    = (float*)d_ws;
  float* xf    = ws;                               // NN*D f32 (h buffer each layer)
  u16*  xl    = (u16*)(xf + (size_t)NN*D);         // NN*D bf16 (in former xl slot)
  u16*  xr    = (u16*)(xf + (size_t)NN*D*2);       // NN*D bf16
  float* prm   = xf + (size_t)NN*D*3;              // 3*PL
  float* pool  = prm + 3*PL;                       // NG*D
  u32*  offs   = (u32*)(pool + NG*D);              // NN+1
  u32*  cursor = offs + (NN + 1);                  // NN
  u32*  csr    = cursor + NN;                      // ET
  u32*  bnd    = csr + ET;                         // NG+1
  u32*  psum   = bnd + (NG + 1);                   // 160
  int*  flags  = (int*)(psum + 160);               // 2

  k_setup<<<169, 256, 0, stream>>>(ei, x, flags, cursor, pool);
  P18 ps;
  for (int i = 0; i < 18; ++i) ps.p[i] = d_in[3 + i];
  k_prep<<<390, 256, 0, stream>>>(ps, prm, flags);

  k_hist<<<ET/256, 256, 0, stream>>>(ei, cursor, flags);
  k_scanA<<<160, 256, 0, stream>>>(cursor, psum);
  k_scanB<<<1, 256, 0, stream>>>(psum, offs, batch, bnd, flags);
  k_scanC<<<160, 256, 0, stream>>>(cursor, offs, psum);
  k_scatter<<<ET/256, 256, 0, stream>>>(ei, cursor, csr, flags);

  for (int l = 0; l < 3; ++l){
    const float* p = prm + (size_t)l*PL;
    const void* Xin = (l == 0) ? x : (const void*)xf;
    k_gemm<<<dim3(NN/128, 2), 256, 0, stream>>>(Xin, p, xl, xr, flags, l == 0);
    k_node<<<NN/4, 256, 0, stream>>>(xl, xr, offs, csr, p, xf, d_out, flags, l == 2);
  }
  k_pool1<<<NG*64, 256, 0, stream>>>(xf, bnd, pool);
  k_pool2<<<8, 256, 0, stream>>>(pool, bnd, d_out, flags);
}